// Round 4
// baseline (487.622 us; speedup 1.0000x reference)
//
#include <hip/hip_runtime.h>
#include <hip/hip_bf16.h>
#include <cstdint>

#define AS1 __attribute__((address_space(1)))
#define AS3 __attribute__((address_space(3)))

typedef __bf16 bf16x8 __attribute__((ext_vector_type(8)));
typedef float  f32x4  __attribute__((ext_vector_type(4)));

__device__ __forceinline__ void gld_lds16(const void* g, void* l) {
    __builtin_amdgcn_global_load_lds((const AS1 void*)g, (AS3 void*)l, 16, 0, 0);
}

// ---------------- Kernel 1: build bf16 GEMM A matrix [256][1152] ----------------
// A[r][k], r = g*32 + o2, k = (ky*3+kx)*128 + c2*8 + hh; value = w2[o2, c2, (g-hh)%8, ky, kx]
__global__ void k_build_a(const float* __restrict__ w2, __hip_bfloat16* __restrict__ A) {
    int i = blockIdx.x * 256 + threadIdx.x;   // grid exact: 256*1152
    int r = i / 1152, k = i - r * 1152;
    int g = r >> 5, o2 = r & 31;
    int kk = k >> 7, cch = k & 127;
    int ky = kk / 3, kx = kk - ky * 3;
    int c2 = cch >> 3, hh = cch & 7;
    int gi = (g - hh) & 7;
    A[i] = __float2bfloat16(w2[((o2 * 16 + c2) * 8 + gi) * 9 + ky * 3 + kx]);
}

// ---------------- Kernel 2: conv1 + relu -> channel-last padded bf16 h ----------------
// Rotation of base weights computed in-block (fp32, exact replica of reference math).
// hl layout: [b][yy 0..29][xx 0..29][c 0..127], borders = 0.
__global__ __launch_bounds__(256) void k_conv1(const float* __restrict__ x,
                                               const float* __restrict__ base,
                                               __hip_bfloat16* __restrict__ hl) {
    __shared__ float w1s[1152];
    int tid = threadIdx.x;
    if (tid < 128) {
        int g = tid >> 4, o = tid & 15;
        float th = 6.28318530717958647692f * (float)g / 8.0f;
        float c = cosf(th), s = sinf(th);
        for (int i = 0; i < 3; ++i) {
            float ys = (2.0f * i + 1.0f) / 3.0f - 1.0f;
            for (int j = 0; j < 3; ++j) {
                float xs = (2.0f * j + 1.0f) / 3.0f - 1.0f;
                float gx = c * xs - s * ys;
                float gy = s * xs + c * ys;
                float px = ((gx + 1.0f) * 3.0f - 1.0f) * 0.5f;
                float py = ((gy + 1.0f) * 3.0f - 1.0f) * 0.5f;
                float x0 = floorf(px), y0 = floorf(py);
                float wx = px - x0, wy = py - y0;
                int x0i = (int)x0, y0i = (int)y0;
                auto gat = [&](int yi, int xi) -> float {
                    bool v = (yi >= 0) && (yi < 3) && (xi >= 0) && (xi < 3);
                    int yc = min(max(yi, 0), 2), xc = min(max(xi, 0), 2);
                    return v ? base[o * 9 + yc * 3 + xc] : 0.0f;
                };
                w1s[tid * 9 + i * 3 + j] =
                      gat(y0i, x0i)         * (1.0f - wx) * (1.0f - wy)
                    + gat(y0i, x0i + 1)     * wx          * (1.0f - wy)
                    + gat(y0i + 1, x0i)     * (1.0f - wx) * wy
                    + gat(y0i + 1, x0i + 1) * wx          * wy;
            }
        }
    }
    __syncthreads();

    const int c0 = (tid & 15) * 8;
    float wreg[8][9];
#pragma unroll
    for (int cc = 0; cc < 8; ++cc)
#pragma unroll
        for (int k = 0; k < 9; ++k) wreg[cc][k] = w1s[(c0 + cc) * 9 + k];

    const int ps = tid >> 4;              // pixel slot 0..15
    const int pbase = blockIdx.x * 64;    // grid 7200 exact -> 512*900 pixels

#pragma unroll
    for (int j = 0; j < 4; ++j) {
        int pi = pbase + j * 16 + ps;
        int xx = pi % 30; int t = pi / 30; int yy = t % 30; int b = t / 30;
        float acc[8] = {0.f,0.f,0.f,0.f,0.f,0.f,0.f,0.f};
        if (xx >= 1 && xx <= 28 && yy >= 1 && yy <= 28) {
            const float* xb = x + b * 784;
            int y = yy - 1, xc = xx - 1;
#pragma unroll
            for (int dy = -1; dy <= 1; ++dy) {
                int sy = y + dy;
#pragma unroll
                for (int dx = -1; dx <= 1; ++dx) {
                    int sx = xc + dx;
                    float xv = (sy >= 0 && sy < 28 && sx >= 0 && sx < 28) ? xb[sy * 28 + sx] : 0.0f;
                    int k = (dy + 1) * 3 + (dx + 1);
#pragma unroll
                    for (int cc = 0; cc < 8; ++cc) acc[cc] += xv * wreg[cc][k];
                }
            }
        }
        union { __hip_bfloat16 h[8]; float4 f4; } u;
#pragma unroll
        for (int cc = 0; cc < 8; ++cc) u.h[cc] = __float2bfloat16(fmaxf(acc[cc], 0.0f));
        *(float4*)(hl + (size_t)pi * 128 + c0) = u.f4;
    }
}

// ---------------- Kernel 3: conv2 implicit GEMM + relu + 8-channel mean -> p ----------------
// Dense-N packing: n = b*784 + y*28 + x. The padded-30 hl layout absorbs (ky,kx) shifts.
__global__ __launch_bounds__(256) void k_conv2(const __hip_bfloat16* __restrict__ A,
                                               const __hip_bfloat16* __restrict__ hl,
                                               float* __restrict__ p) {
    __shared__ __align__(16) char smem[32768];   // As [128][64] bf16 | Bs [128][64] bf16

    const int tid  = threadIdx.x;
    const int lane = tid & 63;
    const int w    = tid >> 6;
    const int wr   = w >> 1, wc = w & 1;
    const int quad = lane >> 4;

    const int mt = blockIdx.x & 1;
    const int nt = blockIdx.x >> 1;      // < 3136
    const int n0 = nt << 7;
    const int r0 = mt << 7;

    uint32_t aG[4], bG[4], ldsOff[4];
#pragma unroll
    for (int q = 0; q < 4; ++q) {
        int ch = w * 4 + q;
        int rl = ch * 8 + (lane >> 3);
        int ca = (lane & 7) ^ (rl & 7);
        aG[q] = (uint32_t)((r0 + rl) * 2304 + ca * 16);
        int n  = n0 + rl;
        int b  = n / 784; int rr = n - b * 784;
        int y  = rr / 28; int xx = rr - y * 28;
        bG[q]  = (uint32_t)(((b * 30 + y) * 30 + xx) * 256 + ca * 16);
        ldsOff[q] = (uint32_t)(ch * 1024);
    }

    uint32_t aro[4], bro[4]; int asw[4], bsw[4];
#pragma unroll
    for (int i = 0; i < 4; ++i) {
        int rl = 64 * wr + 16 * i + (lane & 15);
        aro[i] = (uint32_t)(rl * 128); asw[i] = rl & 7;
        int nl = 64 * wc + 16 * i + (lane & 15);
        bro[i] = (uint32_t)(16384 + nl * 128); bsw[i] = nl & 7;
    }

    f32x4 acc[4][4];
#pragma unroll
    for (int i = 0; i < 4; ++i)
#pragma unroll
        for (int j = 0; j < 4; ++j) acc[i][j] = (f32x4)(0.0f);

    const char* Ab = (const char*)A;
    const char* Hb = (const char*)hl;

    for (int s = 0; s < 18; ++s) {
        int kk = s >> 1, half = s & 1;
        int ky = kk / 3, kx = kk - ky * 3;
        int aoff = kk * 256 + half * 128;
        int boff = (ky * 30 + kx) * 256 + half * 128;

        __syncthreads();
#pragma unroll
        for (int q = 0; q < 4; ++q) {
            gld_lds16(Ab + aG[q] + aoff, smem + ldsOff[q]);
            gld_lds16(Hb + bG[q] + boff, smem + 16384 + ldsOff[q]);
        }
        __syncthreads();

#pragma unroll
        for (int ks = 0; ks < 2; ++ks) {
            int cb = ks * 4 + quad;
            bf16x8 af[4], bf[4];
#pragma unroll
            for (int i = 0; i < 4; ++i) {
                af[i] = *(const bf16x8*)(smem + aro[i] + ((cb ^ asw[i]) * 16));
                bf[i] = *(const bf16x8*)(smem + bro[i] + ((cb ^ bsw[i]) * 16));
            }
#pragma unroll
            for (int i = 0; i < 4; ++i)
#pragma unroll
                for (int j = 0; j < 4; ++j)
                    acc[i][j] = __builtin_amdgcn_mfma_f32_16x16x32_bf16(af[i], bf[j], acc[i][j], 0, 0, 0);
        }
    }

#pragma unroll
    for (int i = 0; i < 4; ++i) {
        int grp = (r0 + 64 * wr + 16 * i) >> 3;
#pragma unroll
        for (int j = 0; j < 4; ++j) {
            f32x4 v = acc[i][j];
            float sv = fmaxf(v[0], 0.0f) + fmaxf(v[1], 0.0f) + fmaxf(v[2], 0.0f) + fmaxf(v[3], 0.0f);
            sv += __shfl_xor(sv, 16, 64);
            if ((quad & 1) == 0) {
                int nl = 64 * wc + 16 * j + (lane & 15);
                int n  = n0 + nl;
                int b  = n / 784; int rr = n - b * 784;
                int a  = grp + (quad >> 1);
                p[(b * 32 + a) * 784 + rr] = sv * 0.125f;
            }
        }
    }
}

// ---------------- Kernel 4: FC, split over batch-groups x k-splits ----------------
// grid = 32 bt * 8 ks. Block (bt,ks): 16 batches, k-range [ks*3136, +3136) floats.
// fc_w traffic: 64 KB/block (32 MB total, was 512 MB). Partials -> atomicAdd(out).
__global__ __launch_bounds__(256) void k_fc1(const float* __restrict__ p,
                                             const float* __restrict__ fw,
                                             const float* __restrict__ fb,
                                             float* __restrict__ out) {
    int bt = blockIdx.x >> 3;
    int ks = blockIdx.x & 7;
    int tid = threadIdx.x;
    int kl = tid & 15, bi = tid >> 4;
    int b = bt * 16 + bi;
    const float4* p4 = (const float4*)(p + (size_t)b * 25088);
    const float4* w4 = (const float4*)fw;
    float acc[10] = {};
#pragma unroll 7
    for (int t = 0; t < 49; ++t) {
        int idx = ks * 784 + kl + t * 16;
        float4 v = p4[idx];
#pragma unroll
        for (int c = 0; c < 10; ++c) {
            float4 u = w4[c * 6272 + idx];
            acc[c] += v.x * u.x + v.y * u.y + v.z * u.z + v.w * u.w;
        }
    }
#pragma unroll
    for (int c = 0; c < 10; ++c) {
        float s = acc[c];
        s += __shfl_down(s, 8, 16);
        s += __shfl_down(s, 4, 16);
        s += __shfl_down(s, 2, 16);
        s += __shfl_down(s, 1, 16);
        if (kl == 0) {
            float add = s + (ks == 0 ? fb[c] : 0.0f);
            atomicAdd(&out[b * 10 + c], add);
        }
    }
}

// ---------------- launch ----------------
extern "C" void kernel_launch(void* const* d_in, const int* in_sizes, int n_in,
                              void* d_out, int out_size, void* d_ws, size_t ws_size,
                              hipStream_t stream) {
    const float* x  = (const float*)d_in[0];
    const float* bw = (const float*)d_in[1];
    const float* w2 = (const float*)d_in[2];
    const float* fw = (const float*)d_in[3];
    const float* fb = (const float*)d_in[4];
    float* out = (float*)d_out;
    char* ws = (char*)d_ws;

    __hip_bfloat16* Amat = (__hip_bfloat16*)(ws + 4608);
    __hip_bfloat16* hl   = (__hip_bfloat16*)(ws + 594432);
    float*          p    = (float*)(ws + 118563328);

    hipMemsetAsync(d_out, 0, (size_t)out_size * sizeof(float), stream);
    k_build_a<<<1152, 256, 0, stream>>>(w2, Amat);
    k_conv1  <<<7200, 256, 0, stream>>>(x, bw, hl);
    k_conv2  <<<6272, 256, 0, stream>>>(Amat, hl, p);
    k_fc1    <<<256,  256, 0, stream>>>(p, fw, fb, out);
}

// Round 5
// 424.095 us; speedup vs baseline: 1.1498x; 1.1498x over previous
//
#include <hip/hip_runtime.h>
#include <hip/hip_bf16.h>
#include <cstdint>

#define AS1 __attribute__((address_space(1)))
#define AS3 __attribute__((address_space(3)))

typedef __bf16 bf16x8 __attribute__((ext_vector_type(8)));
typedef float  f32x4  __attribute__((ext_vector_type(4)));

__device__ __forceinline__ void gld_lds16(const void* g, void* l) {
    __builtin_amdgcn_global_load_lds((const AS1 void*)g, (AS3 void*)l, 16, 0, 0);
}

// ---------------- Kernel 1: conv1 + relu -> channel-last padded bf16 h ----------------
// Also builds the bf16 GEMM A matrix (blocks < 1152) — merged to save a dispatch.
// Rotation of base weights computed in-block (fp32, exact replica of reference math).
// hl layout: [b][yy 0..29][xx 0..29][c 0..127], borders = 0.
__global__ __launch_bounds__(256) void k_conv1(const float* __restrict__ x,
                                               const float* __restrict__ base,
                                               const float* __restrict__ w2,
                                               __hip_bfloat16* __restrict__ hl,
                                               __hip_bfloat16* __restrict__ A) {
    int tid = threadIdx.x;

    // side job: A[r][k], r=g*32+o2, k=(ky*3+kx)*128+c2*8+hh = w2[o2,c2,(g-hh)%8,ky,kx]
    if (blockIdx.x < 1152) {
        int i = blockIdx.x * 256 + tid;
        int r = i / 1152, k = i - r * 1152;
        int g = r >> 5, o2 = r & 31;
        int kk = k >> 7, cch = k & 127;
        int ky = kk / 3, kx = kk - ky * 3;
        int c2 = cch >> 3, hh = cch & 7;
        int gi = (g - hh) & 7;
        A[i] = __float2bfloat16(w2[((o2 * 16 + c2) * 8 + gi) * 9 + ky * 3 + kx]);
    }

    __shared__ float w1s[1152];
    if (tid < 128) {
        int g = tid >> 4, o = tid & 15;
        float th = 6.28318530717958647692f * (float)g / 8.0f;
        float c = cosf(th), s = sinf(th);
        for (int i = 0; i < 3; ++i) {
            float ys = (2.0f * i + 1.0f) / 3.0f - 1.0f;
            for (int j = 0; j < 3; ++j) {
                float xs = (2.0f * j + 1.0f) / 3.0f - 1.0f;
                float gx = c * xs - s * ys;
                float gy = s * xs + c * ys;
                float px = ((gx + 1.0f) * 3.0f - 1.0f) * 0.5f;
                float py = ((gy + 1.0f) * 3.0f - 1.0f) * 0.5f;
                float x0 = floorf(px), y0 = floorf(py);
                float wx = px - x0, wy = py - y0;
                int x0i = (int)x0, y0i = (int)y0;
                auto gat = [&](int yi, int xi) -> float {
                    bool v = (yi >= 0) && (yi < 3) && (xi >= 0) && (xi < 3);
                    int yc = min(max(yi, 0), 2), xc = min(max(xi, 0), 2);
                    return v ? base[o * 9 + yc * 3 + xc] : 0.0f;
                };
                w1s[tid * 9 + i * 3 + j] =
                      gat(y0i, x0i)         * (1.0f - wx) * (1.0f - wy)
                    + gat(y0i, x0i + 1)     * wx          * (1.0f - wy)
                    + gat(y0i + 1, x0i)     * (1.0f - wx) * wy
                    + gat(y0i + 1, x0i + 1) * wx          * wy;
            }
        }
    }
    __syncthreads();

    const int c0 = (tid & 15) * 8;
    float wreg[8][9];
#pragma unroll
    for (int cc = 0; cc < 8; ++cc)
#pragma unroll
        for (int k = 0; k < 9; ++k) wreg[cc][k] = w1s[(c0 + cc) * 9 + k];

    const int ps = tid >> 4;              // pixel slot 0..15
    const int pbase = blockIdx.x * 64;    // grid 7200 exact -> 512*900 pixels

#pragma unroll
    for (int j = 0; j < 4; ++j) {
        int pi = pbase + j * 16 + ps;
        int xx = pi % 30; int t = pi / 30; int yy = t % 30; int b = t / 30;
        float acc[8] = {0.f,0.f,0.f,0.f,0.f,0.f,0.f,0.f};
        if (xx >= 1 && xx <= 28 && yy >= 1 && yy <= 28) {
            const float* xb = x + b * 784;
            int y = yy - 1, xc = xx - 1;
#pragma unroll
            for (int dy = -1; dy <= 1; ++dy) {
                int sy = y + dy;
#pragma unroll
                for (int dx = -1; dx <= 1; ++dx) {
                    int sx = xc + dx;
                    float xv = (sy >= 0 && sy < 28 && sx >= 0 && sx < 28) ? xb[sy * 28 + sx] : 0.0f;
                    int k = (dy + 1) * 3 + (dx + 1);
#pragma unroll
                    for (int cc = 0; cc < 8; ++cc) acc[cc] += xv * wreg[cc][k];
                }
            }
        }
        union { __hip_bfloat16 h[8]; float4 f4; } u;
#pragma unroll
        for (int cc = 0; cc < 8; ++cc) u.h[cc] = __float2bfloat16(fmaxf(acc[cc], 0.0f));
        *(float4*)(hl + (size_t)pi * 128 + c0) = u.f4;
    }
}

// ---------------- Kernel 2: conv2 implicit GEMM + relu + 8-channel mean -> p ----------------
// Dense-N packing: n = b*784 + y*28 + x. Padded-30 hl layout absorbs (ky,kx) shifts.
// XCD-aware swizzle: both mt-halves of an nt land on the same XCD (B-tile L2 reuse).
__global__ __launch_bounds__(256) void k_conv2(const __hip_bfloat16* __restrict__ A,
                                               const __hip_bfloat16* __restrict__ hl,
                                               float* __restrict__ p) {
    __shared__ __align__(16) char smem[32768];   // As [128][64] bf16 | Bs [128][64] bf16

    const int tid  = threadIdx.x;
    const int lane = tid & 63;
    const int w    = tid >> 6;
    const int wr   = w >> 1, wc = w & 1;
    const int quad = lane >> 4;

    // blockIdx -> (nt, mt): dispatch round-robins blockIdx over 8 XCDs.
    // xcd = bid&7, slot = bid>>3; nt = xcd + 8*(slot>>1), mt = slot&1
    // => the two mt of each nt are consecutive slots on ONE xcd.
    const int bid  = blockIdx.x;          // grid 6272 = 8 * 784
    const int xcd  = bid & 7;
    const int slot = bid >> 3;
    const int nt   = xcd + 8 * (slot >> 1);   // < 3136
    const int mt   = slot & 1;
    const int n0 = nt << 7;
    const int r0 = mt << 7;

    uint32_t aG[4], bG[4], ldsOff[4];
#pragma unroll
    for (int q = 0; q < 4; ++q) {
        int ch = w * 4 + q;
        int rl = ch * 8 + (lane >> 3);
        int ca = (lane & 7) ^ (rl & 7);
        aG[q] = (uint32_t)((r0 + rl) * 2304 + ca * 16);
        int n  = n0 + rl;
        int b  = n / 784; int rr = n - b * 784;
        int y  = rr / 28; int xx = rr - y * 28;
        bG[q]  = (uint32_t)(((b * 30 + y) * 30 + xx) * 256 + ca * 16);
        ldsOff[q] = (uint32_t)(ch * 1024);
    }

    uint32_t aro[4], bro[4]; int asw[4], bsw[4];
#pragma unroll
    for (int i = 0; i < 4; ++i) {
        int rl = 64 * wr + 16 * i + (lane & 15);
        aro[i] = (uint32_t)(rl * 128); asw[i] = rl & 7;
        int nl = 64 * wc + 16 * i + (lane & 15);
        bro[i] = (uint32_t)(16384 + nl * 128); bsw[i] = nl & 7;
    }

    f32x4 acc[4][4];
#pragma unroll
    for (int i = 0; i < 4; ++i)
#pragma unroll
        for (int j = 0; j < 4; ++j) acc[i][j] = (f32x4)(0.0f);

    const char* Ab = (const char*)A;
    const char* Hb = (const char*)hl;

    for (int s = 0; s < 18; ++s) {
        int kk = s >> 1, half = s & 1;
        int ky = kk / 3, kx = kk - ky * 3;
        int aoff = kk * 256 + half * 128;
        int boff = (ky * 30 + kx) * 256 + half * 128;

        __syncthreads();
#pragma unroll
        for (int q = 0; q < 4; ++q) {
            gld_lds16(Ab + aG[q] + aoff, smem + ldsOff[q]);
            gld_lds16(Hb + bG[q] + boff, smem + 16384 + ldsOff[q]);
        }
        __syncthreads();

#pragma unroll
        for (int ks = 0; ks < 2; ++ks) {
            int cb = ks * 4 + quad;
            bf16x8 af[4], bf[4];
#pragma unroll
            for (int i = 0; i < 4; ++i) {
                af[i] = *(const bf16x8*)(smem + aro[i] + ((cb ^ asw[i]) * 16));
                bf[i] = *(const bf16x8*)(smem + bro[i] + ((cb ^ bsw[i]) * 16));
            }
#pragma unroll
            for (int i = 0; i < 4; ++i)
#pragma unroll
                for (int j = 0; j < 4; ++j)
                    acc[i][j] = __builtin_amdgcn_mfma_f32_16x16x32_bf16(af[i], bf[j], acc[i][j], 0, 0, 0);
        }
    }

#pragma unroll
    for (int i = 0; i < 4; ++i) {
        int grp = (r0 + 64 * wr + 16 * i) >> 3;
#pragma unroll
        for (int j = 0; j < 4; ++j) {
            f32x4 v = acc[i][j];
            float sv = fmaxf(v[0], 0.0f) + fmaxf(v[1], 0.0f) + fmaxf(v[2], 0.0f) + fmaxf(v[3], 0.0f);
            sv += __shfl_xor(sv, 16, 64);
            if ((quad & 1) == 0) {
                int nl = 64 * wc + 16 * j + (lane & 15);
                int n  = n0 + nl;
                int b  = n / 784; int rr = n - b * 784;
                int a  = grp + (quad >> 1);
                p[(b * 32 + a) * 784 + rr] = sv * 0.125f;
            }
        }
    }
}

// ---------------- Kernel 3: FC (one block per batch; fc_w is 1 MB -> L2-resident) ----------------
__global__ void k_fc(const float* __restrict__ p, const float* __restrict__ fw,
                     const float* __restrict__ fb, float* __restrict__ out) {
    int b = blockIdx.x, tid = threadIdx.x;
    const float4* p4 = (const float4*)(p + (size_t)b * 25088);
    const float4* w4 = (const float4*)fw;
    float acc[10] = {};
    for (int i = tid; i < 6272; i += 256) {
        float4 v = p4[i];
#pragma unroll
        for (int c = 0; c < 10; ++c) {
            float4 u = w4[c * 6272 + i];
            acc[c] += v.x * u.x + v.y * u.y + v.z * u.z + v.w * u.w;
        }
    }
    __shared__ float red[10][4];
    int lane = tid & 63, wv = tid >> 6;
#pragma unroll
    for (int c = 0; c < 10; ++c) {
        float s = acc[c];
#pragma unroll
        for (int o = 32; o > 0; o >>= 1) s += __shfl_down(s, o, 64);
        if (lane == 0) red[c][wv] = s;
    }
    __syncthreads();
    if (tid < 10)
        out[b * 10 + tid] = red[tid][0] + red[tid][1] + red[tid][2] + red[tid][3] + fb[tid];
}

// ---------------- launch ----------------
extern "C" void kernel_launch(void* const* d_in, const int* in_sizes, int n_in,
                              void* d_out, int out_size, void* d_ws, size_t ws_size,
                              hipStream_t stream) {
    const float* x  = (const float*)d_in[0];
    const float* bw = (const float*)d_in[1];
    const float* w2 = (const float*)d_in[2];
    const float* fw = (const float*)d_in[3];
    const float* fb = (const float*)d_in[4];
    float* out = (float*)d_out;
    char* ws = (char*)d_ws;

    __hip_bfloat16* Amat = (__hip_bfloat16*)(ws + 4608);
    __hip_bfloat16* hl   = (__hip_bfloat16*)(ws + 594432);
    float*          p    = (float*)(ws + 118563328);

    k_conv1<<<7200, 256, 0, stream>>>(x, bw, w2, hl, Amat);
    k_conv2<<<6272, 256, 0, stream>>>(Amat, hl, p);
    k_fc   <<<512,  256, 0, stream>>>(p, fw, fb, out);
}

// Round 6
// 396.464 us; speedup vs baseline: 1.2299x; 1.0697x over previous
//
#include <hip/hip_runtime.h>
#include <hip/hip_bf16.h>
#include <cstdint>

#define AS1 __attribute__((address_space(1)))
#define AS3 __attribute__((address_space(3)))

typedef __bf16 bf16x8 __attribute__((ext_vector_type(8)));
typedef float  f32x16 __attribute__((ext_vector_type(16)));

__device__ __forceinline__ void gld_lds16(const void* g, void* l) {
    __builtin_amdgcn_global_load_lds((const AS1 void*)g, (AS3 void*)l, 16, 0, 0);
}

// ---------------- Kernel 1: conv1 + relu -> channel-last padded bf16 h ----------------
// Also builds the bf16 GEMM A matrix (blocks < 1152).
// hl layout: [b][yy 0..29][xx 0..29][c 0..127], borders = 0.
__global__ __launch_bounds__(256) void k_conv1(const float* __restrict__ x,
                                               const float* __restrict__ base,
                                               const float* __restrict__ w2,
                                               __hip_bfloat16* __restrict__ hl,
                                               __hip_bfloat16* __restrict__ A) {
    int tid = threadIdx.x;

    if (blockIdx.x < 1152) {
        int i = blockIdx.x * 256 + tid;
        int r = i / 1152, k = i - r * 1152;
        int g = r >> 5, o2 = r & 31;
        int kk = k >> 7, cch = k & 127;
        int ky = kk / 3, kx = kk - ky * 3;
        int c2 = cch >> 3, hh = cch & 7;
        int gi = (g - hh) & 7;
        A[i] = __float2bfloat16(w2[((o2 * 16 + c2) * 8 + gi) * 9 + ky * 3 + kx]);
    }

    __shared__ float w1s[1152];
    if (tid < 128) {
        int g = tid >> 4, o = tid & 15;
        float th = 6.28318530717958647692f * (float)g / 8.0f;
        float c = cosf(th), s = sinf(th);
        for (int i = 0; i < 3; ++i) {
            float ys = (2.0f * i + 1.0f) / 3.0f - 1.0f;
            for (int j = 0; j < 3; ++j) {
                float xs = (2.0f * j + 1.0f) / 3.0f - 1.0f;
                float gx = c * xs - s * ys;
                float gy = s * xs + c * ys;
                float px = ((gx + 1.0f) * 3.0f - 1.0f) * 0.5f;
                float py = ((gy + 1.0f) * 3.0f - 1.0f) * 0.5f;
                float x0 = floorf(px), y0 = floorf(py);
                float wx = px - x0, wy = py - y0;
                int x0i = (int)x0, y0i = (int)y0;
                auto gat = [&](int yi, int xi) -> float {
                    bool v = (yi >= 0) && (yi < 3) && (xi >= 0) && (xi < 3);
                    int yc = min(max(yi, 0), 2), xc = min(max(xi, 0), 2);
                    return v ? base[o * 9 + yc * 3 + xc] : 0.0f;
                };
                w1s[tid * 9 + i * 3 + j] =
                      gat(y0i, x0i)         * (1.0f - wx) * (1.0f - wy)
                    + gat(y0i, x0i + 1)     * wx          * (1.0f - wy)
                    + gat(y0i + 1, x0i)     * (1.0f - wx) * wy
                    + gat(y0i + 1, x0i + 1) * wx          * wy;
            }
        }
    }
    __syncthreads();

    const int c0 = (tid & 15) * 8;
    float wreg[8][9];
#pragma unroll
    for (int cc = 0; cc < 8; ++cc)
#pragma unroll
        for (int k = 0; k < 9; ++k) wreg[cc][k] = w1s[(c0 + cc) * 9 + k];

    const int ps = tid >> 4;
    const int pbase = blockIdx.x * 64;    // grid 7200 exact -> 512*900 pixels

#pragma unroll
    for (int j = 0; j < 4; ++j) {
        int pi = pbase + j * 16 + ps;
        int xx = pi % 30; int t = pi / 30; int yy = t % 30; int b = t / 30;
        float acc[8] = {0.f,0.f,0.f,0.f,0.f,0.f,0.f,0.f};
        if (xx >= 1 && xx <= 28 && yy >= 1 && yy <= 28) {
            const float* xb = x + b * 784;
            int y = yy - 1, xc = xx - 1;
#pragma unroll
            for (int dy = -1; dy <= 1; ++dy) {
                int sy = y + dy;
#pragma unroll
                for (int dx = -1; dx <= 1; ++dx) {
                    int sx = xc + dx;
                    float xv = (sy >= 0 && sy < 28 && sx >= 0 && sx < 28) ? xb[sy * 28 + sx] : 0.0f;
                    int k = (dy + 1) * 3 + (dx + 1);
#pragma unroll
                    for (int cc = 0; cc < 8; ++cc) acc[cc] += xv * wreg[cc][k];
                }
            }
        }
        union { __hip_bfloat16 h[8]; float4 f4; } u;
#pragma unroll
        for (int cc = 0; cc < 8; ++cc) u.h[cc] = __float2bfloat16(fmaxf(acc[cc], 0.0f));
        *(float4*)(hl + (size_t)pi * 128 + c0) = u.f4;
    }
}

// ---------------- Kernel 2: conv2 implicit GEMM (32x32x16 MFMA) + relu + pool -> p ----------------
// Dense-N packing: n = b*784 + y*28 + x. Padded-30 hl layout absorbs (ky,kx) shifts.
// XCD-aware swizzle keeps both mt-halves of an nt on one XCD.
// Wave = 64x64 (2x2 tiles of 32x32). C layout: col=lane&31, row=(reg&3)+8*(reg>>2)+4*(lane>>5).
__global__ __launch_bounds__(256) void k_conv2(const __hip_bfloat16* __restrict__ A,
                                               const __hip_bfloat16* __restrict__ hl,
                                               float* __restrict__ p) {
    __shared__ __align__(16) char smem[32768];   // As [128][64] bf16 | Bs [128][64] bf16

    const int tid  = threadIdx.x;
    const int lane = tid & 63;
    const int w    = tid >> 6;
    const int wr   = w >> 1, wc = w & 1;
    const int hi   = lane >> 5;           // K-half selector for A/B frags

    const int bid  = blockIdx.x;          // grid 6272 = 8 * 784
    const int xcd  = bid & 7;
    const int slot = bid >> 3;
    const int nt   = xcd + 8 * (slot >> 1);   // < 3136
    const int mt   = slot & 1;
    const int n0 = nt << 7;
    const int r0 = mt << 7;

    // staging constants (unchanged layout)
    uint32_t aG[4], bG[4], ldsOff[4];
#pragma unroll
    for (int q = 0; q < 4; ++q) {
        int ch = w * 4 + q;
        int rl = ch * 8 + (lane >> 3);
        int ca = (lane & 7) ^ (rl & 7);
        aG[q] = (uint32_t)((r0 + rl) * 2304 + ca * 16);
        int n  = n0 + rl;
        int b  = n / 784; int rr = n - b * 784;
        int y  = rr / 28; int xx = rr - y * 28;
        bG[q]  = (uint32_t)(((b * 30 + y) * 30 + xx) * 256 + ca * 16);
        ldsOff[q] = (uint32_t)(ch * 1024);
    }

    // fragment-read constants: A rows / B cols per tile
    uint32_t aro[2], bro[2]; int asw[2], bsw[2];
#pragma unroll
    for (int t = 0; t < 2; ++t) {
        int rl = 64 * wr + 32 * t + (lane & 31);
        aro[t] = (uint32_t)(rl * 128); asw[t] = rl & 7;
        int nl = 64 * wc + 32 * t + (lane & 31);
        bro[t] = (uint32_t)(16384 + nl * 128); bsw[t] = nl & 7;
    }

    f32x16 acc[2][2];
#pragma unroll
    for (int i = 0; i < 2; ++i)
#pragma unroll
        for (int j = 0; j < 2; ++j) acc[i][j] = (f32x16)(0.0f);

    const char* Ab = (const char*)A;
    const char* Hb = (const char*)hl;

    for (int s = 0; s < 18; ++s) {
        int kk = s >> 1, half = s & 1;
        int ky = kk / 3, kx = kk - ky * 3;
        int aoff = kk * 256 + half * 128;
        int boff = (ky * 30 + kx) * 256 + half * 128;

        __syncthreads();
#pragma unroll
        for (int q = 0; q < 4; ++q) {
            gld_lds16(Ab + aG[q] + aoff, smem + ldsOff[q]);
            gld_lds16(Hb + bG[q] + boff, smem + 16384 + ldsOff[q]);
        }
        __syncthreads();

#pragma unroll
        for (int kstep = 0; kstep < 4; ++kstep) {
            int cb = kstep * 2 + hi;      // 16B-chunk index within the 64-K stage
            bf16x8 af[2], bf[2];
#pragma unroll
            for (int t = 0; t < 2; ++t) {
                af[t] = *(const bf16x8*)(smem + aro[t] + ((cb ^ asw[t]) * 16));
                bf[t] = *(const bf16x8*)(smem + bro[t] + ((cb ^ bsw[t]) * 16));
            }
#pragma unroll
            for (int i = 0; i < 2; ++i)
#pragma unroll
                for (int j = 0; j < 2; ++j)
                    acc[i][j] = __builtin_amdgcn_mfma_f32_32x32x16_bf16(af[i], bf[j], acc[i][j], 0, 0, 0);
        }
    }

    // epilogue: relu + mean over 8 consecutive M-rows.
    // Tile rows 8q..8q+3 + 4*hi live in regs 4q..4q+3; partner half via shfl_xor 32.
#pragma unroll
    for (int ti = 0; ti < 2; ++ti) {
        int gbase = (r0 + 64 * wr + 32 * ti) >> 3;
#pragma unroll
        for (int tj = 0; tj < 2; ++tj) {
            f32x16 v = acc[ti][tj];
#pragma unroll
            for (int q = 0; q < 4; ++q) {
                float s = fmaxf(v[4*q], 0.0f) + fmaxf(v[4*q+1], 0.0f)
                        + fmaxf(v[4*q+2], 0.0f) + fmaxf(v[4*q+3], 0.0f);
                s += __shfl_xor(s, 32, 64);
                if (hi == 0) {
                    int a = gbase + q;
                    int n = n0 + 64 * wc + 32 * tj + (lane & 31);
                    int b = n / 784; int rr = n - b * 784;
                    p[(b * 32 + a) * 784 + rr] = s * 0.125f;
                }
            }
        }
    }
}

// ---------------- Kernel 3: FC, 4-way k-split, atomicAdd into zeroed out ----------------
__global__ __launch_bounds__(256) void k_fc(const float* __restrict__ p,
                                            const float* __restrict__ fw,
                                            const float* __restrict__ fb,
                                            float* __restrict__ out) {
    int b = blockIdx.x >> 2, ks = blockIdx.x & 3;
    int tid = threadIdx.x;
    const float4* p4 = (const float4*)(p + (size_t)b * 25088);
    const float4* w4 = (const float4*)fw;
    float acc[10] = {};
    for (int i = ks * 1568 + tid; i < (ks + 1) * 1568; i += 256) {
        float4 v = p4[i];
#pragma unroll
        for (int c = 0; c < 10; ++c) {
            float4 u = w4[c * 6272 + i];
            acc[c] += v.x * u.x + v.y * u.y + v.z * u.z + v.w * u.w;
        }
    }
    __shared__ float red[10][4];
    int lane = tid & 63, wv = tid >> 6;
#pragma unroll
    for (int c = 0; c < 10; ++c) {
        float s = acc[c];
#pragma unroll
        for (int o = 32; o > 0; o >>= 1) s += __shfl_down(s, o, 64);
        if (lane == 0) red[c][wv] = s;
    }
    __syncthreads();
    if (tid < 10) {
        float s = red[tid][0] + red[tid][1] + red[tid][2] + red[tid][3];
        if (ks == 0) s += fb[tid];
        atomicAdd(&out[b * 10 + tid], s);
    }
}

// ---------------- launch ----------------
extern "C" void kernel_launch(void* const* d_in, const int* in_sizes, int n_in,
                              void* d_out, int out_size, void* d_ws, size_t ws_size,
                              hipStream_t stream) {
    const float* x  = (const float*)d_in[0];
    const float* bw = (const float*)d_in[1];
    const float* w2 = (const float*)d_in[2];
    const float* fw = (const float*)d_in[3];
    const float* fb = (const float*)d_in[4];
    float* out = (float*)d_out;
    char* ws = (char*)d_ws;

    __hip_bfloat16* Amat = (__hip_bfloat16*)(ws + 4608);
    __hip_bfloat16* hl   = (__hip_bfloat16*)(ws + 594432);
    float*          p    = (float*)(ws + 118563328);

    hipMemsetAsync(d_out, 0, (size_t)out_size * sizeof(float), stream);
    k_conv1<<<7200, 256, 0, stream>>>(x, bw, w2, hl, Amat);
    k_conv2<<<6272, 256, 0, stream>>>(Amat, hl, p);
    k_fc   <<<2048, 256, 0, stream>>>(p, fw, fb, out);
}

// Round 7
// 392.367 us; speedup vs baseline: 1.2428x; 1.0104x over previous
//
#include <hip/hip_runtime.h>
#include <hip/hip_bf16.h>
#include <cstdint>

#define AS1 __attribute__((address_space(1)))
#define AS3 __attribute__((address_space(3)))

typedef __bf16 bf16x8 __attribute__((ext_vector_type(8)));
typedef float  f32x16 __attribute__((ext_vector_type(16)));

__device__ __forceinline__ void gld_lds16(const void* g, void* l) {
    __builtin_amdgcn_global_load_lds((const AS1 void*)g, (AS3 void*)l, 16, 0, 0);
}

// ---------------- Kernel 1: conv1 + relu -> channel-last padded bf16 h ----------------
// Also builds the bf16 GEMM A matrix (blocks < 1152).
// hl layout: [b][yy 0..29][xx 0..29][c 0..127], borders = 0.
__global__ __launch_bounds__(256) void k_conv1(const float* __restrict__ x,
                                               const float* __restrict__ base,
                                               const float* __restrict__ w2,
                                               __hip_bfloat16* __restrict__ hl,
                                               __hip_bfloat16* __restrict__ A) {
    int tid = threadIdx.x;

    if (blockIdx.x < 1152) {
        int i = blockIdx.x * 256 + tid;
        int r = i / 1152, k = i - r * 1152;
        int g = r >> 5, o2 = r & 31;
        int kk = k >> 7, cch = k & 127;
        int ky = kk / 3, kx = kk - ky * 3;
        int c2 = cch >> 3, hh = cch & 7;
        int gi = (g - hh) & 7;
        A[i] = __float2bfloat16(w2[((o2 * 16 + c2) * 8 + gi) * 9 + ky * 3 + kx]);
    }

    __shared__ float w1s[1152];
    if (tid < 128) {
        int g = tid >> 4, o = tid & 15;
        float th = 6.28318530717958647692f * (float)g / 8.0f;
        float c = cosf(th), s = sinf(th);
        for (int i = 0; i < 3; ++i) {
            float ys = (2.0f * i + 1.0f) / 3.0f - 1.0f;
            for (int j = 0; j < 3; ++j) {
                float xs = (2.0f * j + 1.0f) / 3.0f - 1.0f;
                float gx = c * xs - s * ys;
                float gy = s * xs + c * ys;
                float px = ((gx + 1.0f) * 3.0f - 1.0f) * 0.5f;
                float py = ((gy + 1.0f) * 3.0f - 1.0f) * 0.5f;
                float x0 = floorf(px), y0 = floorf(py);
                float wx = px - x0, wy = py - y0;
                int x0i = (int)x0, y0i = (int)y0;
                auto gat = [&](int yi, int xi) -> float {
                    bool v = (yi >= 0) && (yi < 3) && (xi >= 0) && (xi < 3);
                    int yc = min(max(yi, 0), 2), xc = min(max(xi, 0), 2);
                    return v ? base[o * 9 + yc * 3 + xc] : 0.0f;
                };
                w1s[tid * 9 + i * 3 + j] =
                      gat(y0i, x0i)         * (1.0f - wx) * (1.0f - wy)
                    + gat(y0i, x0i + 1)     * wx          * (1.0f - wy)
                    + gat(y0i + 1, x0i)     * (1.0f - wx) * wy
                    + gat(y0i + 1, x0i + 1) * wx          * wy;
            }
        }
    }
    __syncthreads();

    const int c0 = (tid & 15) * 8;
    float wreg[8][9];
#pragma unroll
    for (int cc = 0; cc < 8; ++cc)
#pragma unroll
        for (int k = 0; k < 9; ++k) wreg[cc][k] = w1s[(c0 + cc) * 9 + k];

    const int ps = tid >> 4;
    const int pbase = blockIdx.x * 64;    // grid 7200 exact -> 512*900 pixels

#pragma unroll
    for (int j = 0; j < 4; ++j) {
        int pi = pbase + j * 16 + ps;
        int xx = pi % 30; int t = pi / 30; int yy = t % 30; int b = t / 30;
        float acc[8] = {0.f,0.f,0.f,0.f,0.f,0.f,0.f,0.f};
        if (xx >= 1 && xx <= 28 && yy >= 1 && yy <= 28) {
            const float* xb = x + b * 784;
            int y = yy - 1, xc = xx - 1;
#pragma unroll
            for (int dy = -1; dy <= 1; ++dy) {
                int sy = y + dy;
#pragma unroll
                for (int dx = -1; dx <= 1; ++dx) {
                    int sx = xc + dx;
                    float xv = (sy >= 0 && sy < 28 && sx >= 0 && sx < 28) ? xb[sy * 28 + sx] : 0.0f;
                    int k = (dy + 1) * 3 + (dx + 1);
#pragma unroll
                    for (int cc = 0; cc < 8; ++cc) acc[cc] += xv * wreg[cc][k];
                }
            }
        }
        union { __hip_bfloat16 h[8]; float4 f4; } u;
#pragma unroll
        for (int cc = 0; cc < 8; ++cc) u.h[cc] = __float2bfloat16(fmaxf(acc[cc], 0.0f));
        *(float4*)(hl + (size_t)pi * 128 + c0) = u.f4;
    }
}

// ---------------- Kernel 2: conv2 implicit GEMM (32x32x16 MFMA) + relu + pool -> p(bf16) ----
// Dense-N packing: n = b*784 + y*28 + x. Padded-30 hl layout absorbs (ky,kx) shifts.
// XCD-aware swizzle keeps both mt-halves of an nt on one XCD.
// Bank swizzle includes (row>>3)&3 so lanes {l,l+8,l+16,l+24} hit distinct banks.
__global__ __launch_bounds__(256) void k_conv2(const __hip_bfloat16* __restrict__ A,
                                               const __hip_bfloat16* __restrict__ hl,
                                               __hip_bfloat16* __restrict__ p) {
    __shared__ __align__(16) char smem[32768];   // As [128][64] bf16 | Bs [128][64] bf16

    const int tid  = threadIdx.x;
    const int lane = tid & 63;
    const int w    = tid >> 6;
    const int wr   = w >> 1, wc = w & 1;
    const int hi   = lane >> 5;           // K-half selector for A/B frags

    const int bid  = blockIdx.x;          // grid 6272 = 8 * 784
    const int xcd  = bid & 7;
    const int slot = bid >> 3;
    const int nt   = xcd + 8 * (slot >> 1);   // < 3136
    const int mt   = slot & 1;
    const int n0 = nt << 7;
    const int r0 = mt << 7;

    // staging constants: lane fetches chunk ca so LDS slot low3 = c ^ (r&7) ^ ((r>>3)&3)
    uint32_t aG[4], bG[4], ldsOff[4];
#pragma unroll
    for (int q = 0; q < 4; ++q) {
        int ch = w * 4 + q;
        int rl = ch * 8 + (lane >> 3);
        int ca = (lane & 7) ^ (rl & 7) ^ (ch & 3);
        aG[q] = (uint32_t)((r0 + rl) * 2304 + ca * 16);
        int n  = n0 + rl;
        int b  = n / 784; int rr = n - b * 784;
        int y  = rr / 28; int xx = rr - y * 28;
        bG[q]  = (uint32_t)(((b * 30 + y) * 30 + xx) * 256 + ca * 16);
        ldsOff[q] = (uint32_t)(ch * 1024);
    }

    // fragment-read constants
    uint32_t aro[2], bro[2]; int asw[2], bsw[2];
#pragma unroll
    for (int t = 0; t < 2; ++t) {
        int rl = 64 * wr + 32 * t + (lane & 31);
        aro[t] = (uint32_t)(rl * 128); asw[t] = (rl & 7) ^ ((rl >> 3) & 3);
        int nl = 64 * wc + 32 * t + (lane & 31);
        bro[t] = (uint32_t)(16384 + nl * 128); bsw[t] = (nl & 7) ^ ((nl >> 3) & 3);
    }

    f32x16 acc[2][2];
#pragma unroll
    for (int i = 0; i < 2; ++i)
#pragma unroll
        for (int j = 0; j < 2; ++j) acc[i][j] = (f32x16)(0.0f);

    const char* Ab = (const char*)A;
    const char* Hb = (const char*)hl;

    for (int s = 0; s < 18; ++s) {
        int kk = s >> 1, half = s & 1;
        int ky = kk / 3, kx = kk - ky * 3;
        int aoff = kk * 256 + half * 128;
        int boff = (ky * 30 + kx) * 256 + half * 128;

        __syncthreads();
#pragma unroll
        for (int q = 0; q < 4; ++q) {
            gld_lds16(Ab + aG[q] + aoff, smem + ldsOff[q]);
            gld_lds16(Hb + bG[q] + boff, smem + 16384 + ldsOff[q]);
        }
        __syncthreads();

#pragma unroll
        for (int kstep = 0; kstep < 4; ++kstep) {
            int cb = kstep * 2 + hi;      // 16B-chunk index within the 64-K stage
            bf16x8 af[2], bf[2];
#pragma unroll
            for (int t = 0; t < 2; ++t) {
                af[t] = *(const bf16x8*)(smem + aro[t] + ((cb ^ asw[t]) * 16));
                bf[t] = *(const bf16x8*)(smem + bro[t] + ((cb ^ bsw[t]) * 16));
            }
#pragma unroll
            for (int i = 0; i < 2; ++i)
#pragma unroll
                for (int j = 0; j < 2; ++j)
                    acc[i][j] = __builtin_amdgcn_mfma_f32_32x32x16_bf16(af[i], bf[j], acc[i][j], 0, 0, 0);
        }
    }

    // epilogue: relu + mean over 8 consecutive M-rows; bf16 store.
#pragma unroll
    for (int ti = 0; ti < 2; ++ti) {
        int gbase = (r0 + 64 * wr + 32 * ti) >> 3;
#pragma unroll
        for (int tj = 0; tj < 2; ++tj) {
            f32x16 v = acc[ti][tj];
#pragma unroll
            for (int q = 0; q < 4; ++q) {
                float s = fmaxf(v[4*q], 0.0f) + fmaxf(v[4*q+1], 0.0f)
                        + fmaxf(v[4*q+2], 0.0f) + fmaxf(v[4*q+3], 0.0f);
                s += __shfl_xor(s, 32, 64);
                if (hi == 0) {
                    int a = gbase + q;
                    int n = n0 + 64 * wc + 32 * tj + (lane & 31);
                    int b = n / 784; int rr = n - b * 784;
                    p[(b * 32 + a) * 784 + rr] = __float2bfloat16(s * 0.125f);
                }
            }
        }
    }
}

// ---------------- Kernel 3: FC — w staged in LDS, 16 k-splits x 32 batch-groups ----------------
// Block (bb,ks): 16 batches, k-slice [ks*1568, +1568) floats. w slice 62.7 KB in LDS,
// read ONCE per block (w L2 traffic ~2 MB vs 512 MB). p read as bf16x8.
__global__ __launch_bounds__(256) void k_fc(const __hip_bfloat16* __restrict__ p,
                                            const float* __restrict__ fw,
                                            const float* __restrict__ fb,
                                            float* __restrict__ out) {
    __shared__ float4 wl[3920];           // [10][392] float4
    const int bb = blockIdx.x >> 4;
    const int ks = blockIdx.x & 15;
    const int tid = threadIdx.x;
    const float4* w4 = (const float4*)fw;
    for (int i = tid; i < 3920; i += 256) {
        int c = i / 392, j = i - c * 392;
        wl[i] = w4[c * 6272 + ks * 392 + j];
    }
    __syncthreads();

    const int kl = tid & 15, bi = tid >> 4;
    const int b = bb * 16 + bi;
    const bf16x8* pb = (const bf16x8*)(p + (size_t)b * 25088 + ks * 1568);
    float acc[10] = {};
    for (int t = kl; t < 196; t += 16) {     // 196 bf16x8 chunks per slice
        union { bf16x8 v; __hip_bfloat16 h[8]; } u;
        u.v = pb[t];
        float vf[8];
#pragma unroll
        for (int e = 0; e < 8; ++e) vf[e] = __bfloat162float(u.h[e]);
#pragma unroll
        for (int c = 0; c < 10; ++c) {
            float4 u0 = wl[c * 392 + 2 * t];
            float4 u1 = wl[c * 392 + 2 * t + 1];
            acc[c] += vf[0] * u0.x + vf[1] * u0.y + vf[2] * u0.z + vf[3] * u0.w
                    + vf[4] * u1.x + vf[5] * u1.y + vf[6] * u1.z + vf[7] * u1.w;
        }
    }
#pragma unroll
    for (int c = 0; c < 10; ++c) {
        float s = acc[c];
        s += __shfl_down(s, 8, 16);
        s += __shfl_down(s, 4, 16);
        s += __shfl_down(s, 2, 16);
        s += __shfl_down(s, 1, 16);
        if (kl == 0) {
            if (ks == 0) s += fb[c];
            atomicAdd(&out[b * 10 + c], s);
        }
    }
}

// ---------------- launch ----------------
extern "C" void kernel_launch(void* const* d_in, const int* in_sizes, int n_in,
                              void* d_out, int out_size, void* d_ws, size_t ws_size,
                              hipStream_t stream) {
    const float* x  = (const float*)d_in[0];
    const float* bw = (const float*)d_in[1];
    const float* w2 = (const float*)d_in[2];
    const float* fw = (const float*)d_in[3];
    const float* fb = (const float*)d_in[4];
    float* out = (float*)d_out;
    char* ws = (char*)d_ws;

    __hip_bfloat16* Amat = (__hip_bfloat16*)(ws + 4608);
    __hip_bfloat16* hl   = (__hip_bfloat16*)(ws + 594432);
    __hip_bfloat16* p    = (__hip_bfloat16*)(ws + 118563328);

    hipMemsetAsync(d_out, 0, (size_t)out_size * sizeof(float), stream);
    k_conv1<<<7200, 256, 0, stream>>>(x, bw, w2, hl, Amat);
    k_conv2<<<6272, 256, 0, stream>>>(Amat, hl, p);
    k_fc   <<<512,  256, 0, stream>>>(p, fw, fb, out);
}